// Round 5
// baseline (252.561 us; speedup 1.0000x reference)
//
#include <hip/hip_runtime.h>

#define SEQ    2048
#define NHEAD  16
#define HDIM   64
#define DMODEL 1024
#define BATCH  2

typedef __bf16 bf16;
typedef __bf16 bf16x8 __attribute__((ext_vector_type(8)));
typedef __bf16 bf16x4v __attribute__((ext_vector_type(4)));
typedef float  f32x4  __attribute__((ext_vector_type(4)));

typedef const __attribute__((address_space(1))) void* gas_ptr;
typedef __attribute__((address_space(3))) void*       las_ptr;

__device__ __forceinline__ f32x4 mfma16(bf16x8 a, bf16x8 b, f32x4 c) {
  return __builtin_amdgcn_mfma_f32_16x16x32_bf16(a, b, c, 0, 0, 0);
}

__device__ __forceinline__ void gload_lds16(const void* g, void* l) {
  __builtin_amdgcn_global_load_lds((gas_ptr)(unsigned long long)g,
                                   (las_ptr)(unsigned long long)l, 16, 0, 0);
}

// ---------------- fp32 -> bf16 conversion (x | w_qkv | w_proj concatenated) ----
__global__ void convert_all(const float* __restrict__ x, const float* __restrict__ wq,
                            const float* __restrict__ wp, bf16* __restrict__ out) {
  const long long NX = 4194304, NQ = 3145728, NP = 1048576;
  long long i = ((long long)blockIdx.x * blockDim.x + threadIdx.x) * 4;
  if (i >= NX + NQ + NP) return;
  const float* src; long long off;
  if (i < NX)           { src = x;  off = i; }
  else if (i < NX + NQ) { src = wq; off = i - NX; }
  else                  { src = wp; off = i - NX - NQ; }
  float4 f = *reinterpret_cast<const float4*>(src + off);
  bf16x4v r;
  r[0] = (bf16)f.x; r[1] = (bf16)f.y; r[2] = (bf16)f.z; r[3] = (bf16)f.w;
  *reinterpret_cast<bf16x4v*>(out + i) = r;
}

// ---------------- GEMM C = A(M,K) * B(N,K)^T, bf16 in, fp32 acc ---------------
// EPI 0: epilogue scatters Q/K (fragment-ordered, Q pre-scaled) and V^T
//        (fragment-ordered) so the attention kernel reads contiguous 1KB
//        fragments per wave. EPI 1: proj + bias, fp32 out.
template <int EPI>
__global__ __launch_bounds__(256) void gemm_bt(
    const bf16* __restrict__ A, const bf16* __restrict__ B, int K,
    bf16* __restrict__ q, bf16* __restrict__ k, bf16* __restrict__ v,
    const float* __restrict__ bias, float* __restrict__ out) {
  __shared__ alignas(16) bf16 As[2][128 * 32];
  __shared__ alignas(16) bf16 Bs[2][128 * 32];

  const int tid = threadIdx.x;
  const int l = tid & 63, w = tid >> 6;
  const int lr = l & 15, lg = l >> 4;
  const int wr = (w >> 1) * 64, wc = (w & 1) * 64;
  const long long m0 = (long long)blockIdx.x * 128;
  const long long n0 = (long long)blockIdx.y * 128;
  const int crow = tid >> 2, ccol = (tid & 3) * 8;

  auto stage = [&](int kt, int buf) {
    const bf16* a_src = A + (m0 + crow) * K + (long long)kt * 32 + ccol;
    const bf16* b_src = B + (n0 + crow) * K + (long long)kt * 32 + ccol;
    gload_lds16(a_src,           &As[buf][tid * 8]);
    gload_lds16(a_src + 64LL * K, &As[buf][(tid + 256) * 8]);
    gload_lds16(b_src,           &Bs[buf][tid * 8]);
    gload_lds16(b_src + 64LL * K, &Bs[buf][(tid + 256) * 8]);
  };

  f32x4 acc[4][4];
  const f32x4 fz = {0.f, 0.f, 0.f, 0.f};
#pragma unroll
  for (int m = 0; m < 4; ++m)
#pragma unroll
    for (int n = 0; n < 4; ++n) acc[m][n] = fz;

  stage(0, 0);
  const int nk = K >> 5;
  int cur = 0;
  for (int kt = 0; kt < nk; ++kt) {
    __syncthreads();  // drains vmcnt: buf[cur] staged; prev compute done
    if (kt + 1 < nk) stage(kt + 1, cur ^ 1);
    bf16x8 af[4], bfv[4];
#pragma unroll
    for (int m = 0; m < 4; ++m)
      af[m] = *reinterpret_cast<const bf16x8*>(&As[cur][(wr + m * 16 + lr) * 32 + lg * 8]);
#pragma unroll
    for (int n = 0; n < 4; ++n)
      bfv[n] = *reinterpret_cast<const bf16x8*>(&Bs[cur][(wc + n * 16 + lr) * 32 + lg * 8]);
#pragma unroll
    for (int m = 0; m < 4; ++m)
#pragma unroll
      for (int n = 0; n < 4; ++n) acc[m][n] = mfma16(af[m], bfv[n], acc[m][n]);
    cur ^= 1;
  }

#pragma unroll
  for (int m = 0; m < 4; ++m) {
#pragma unroll
    for (int n = 0; n < 4; ++n) {
#pragma unroll
      for (int j = 0; j < 4; ++j) {
        long long grow = m0 + wr + m * 16 + lg * 4 + j;   // row in (B*S)
        long long gcol = n0 + wc + n * 16 + lr;           // col in N
        float val = acc[m][n][j];
        if (EPI == 0) {
          int three = (int)(gcol >> 10);
          int rem = (int)(gcol & 1023);
          int h = rem >> 6, d = rem & 63;
          int b = (int)(grow >> 11), s = (int)(grow & 2047);
          int bh = b * NHEAD + h;
          if (three < 2) {
            // Q/K fragment order: [bh][s/16][d/32][ (s&15)*32 + ((d>>3)&3)*8 + (d&7) ]
            int dst = ((bh * 128 + (s >> 4)) * 2 + (d >> 5)) * 512 +
                      (s & 15) * 32 + ((d >> 3) & 3) * 8 + (d & 7);
            if (three == 0) q[dst] = (bf16)(val * 0.125f);   // pre-scale Q
            else            k[dst] = (bf16)val;
          } else {
            // V^T fragment order: [bh][d/16][s/64][(s>>5)&1][ (d&15)*32 + ((s>>3)&3)*8 + (s&7) ]
            int dst = (((bh * 4 + (d >> 4)) * 32 + (s >> 6)) * 2 + ((s >> 5) & 1)) * 512 +
                      (d & 15) * 32 + ((s >> 3) & 3) * 8 + (s & 7);
            v[dst] = (bf16)val;
          }
        } else {
          out[grow * 1024 + gcol] = val + bias[gcol];
        }
      }
    }
  }
}

// ---------------- causal flash attention, bf16, hd=64 -------------------------
// Barrier-free: waves fully independent, each owns one 16-row q-tile.
// All Q/K/V^T reads are fragment-ordered contiguous 1KB wave-loads from global.
// Defensive vs round-3 NaN: no uninitialized fragments / guarded MFMAs
// (all loads+MFMAs unconditional, elementwise mask only), and Pl stride 72
// so every bf16x8 LDS access is 16B-aligned.
__global__ __launch_bounds__(256, 4) void attn_kernel(
    const bf16* __restrict__ qbuf, const bf16* __restrict__ kbuf,
    const bf16* __restrict__ vbuf, bf16* __restrict__ ctx) {
  const int lid = blockIdx.y * gridDim.x + blockIdx.x;      // [0,1024)
  const int bh = (lid & 7) + ((lid >> 8) << 3);             // 4 bh per XCD slot
  const int bx = (lid >> 3) & 31;                           // q-group (64 rows)
  const int tid = threadIdx.x;
  const int l = tid & 63, w = tid >> 6;
  const int lr = l & 15, lg = l >> 4;
  const int foff = lr * 32 + lg * 8;

  __shared__ alignas(16) bf16 Pl[4][16][72];   // 144B row stride: 16B-aligned b128

  const int qt16 = bx * 4 + w;                 // wave's 16-row q-tile
  const int qr0 = qt16 * 16;

  const bf16* Qb = qbuf + (bh * 128 + qt16) * 1024 + foff;
  const bf16* Kb = kbuf + bh * 131072 + foff;          // bh*128*2*512
  const bf16* Vb = vbuf + bh * 131072 + foff;          // bh*4*32*2*512

  bf16x8 qf[2];
  qf[0] = *reinterpret_cast<const bf16x8*>(Qb);
  qf[1] = *reinterpret_cast<const bf16x8*>(Qb + 512);

  const f32x4 fz = {0.f, 0.f, 0.f, 0.f};
  f32x4 o[4];
  float mrow[4], lrow[4];
#pragma unroll
  for (int nd = 0; nd < 4; ++nd) o[nd] = fz;
#pragma unroll
  for (int j = 0; j < 4; ++j) { mrow[j] = -1e30f; lrow[j] = 0.f; }

  for (int kt = 0; kt <= bx; ++kt) {
    const bool diag = (kt == bx);

    // V^T fragments first (consumed last -> deepest in flight)
    bf16x8 vf[4][2];
#pragma unroll
    for (int nd = 0; nd < 4; ++nd)
#pragma unroll
      for (int kk = 0; kk < 2; ++kk)
        vf[nd][kk] = *reinterpret_cast<const bf16x8*>(
            &Vb[((nd * 32 + kt) * 2 + kk) * 512]);

    // K fragments (unconditional: in-bounds; avoids undef-under-branch UB)
    bf16x8 kf[4][2];
#pragma unroll
    for (int n = 0; n < 4; ++n)
#pragma unroll
      for (int kk = 0; kk < 2; ++kk)
        kf[n][kk] = *reinterpret_cast<const bf16x8*>(
            &Kb[((kt * 4 + n) * 2 + kk) * 512]);

    // QK^T (all groups), then elementwise causal mask on the diagonal tile
    f32x4 s4[4];
#pragma unroll
    for (int n = 0; n < 4; ++n)
      s4[n] = mfma16(qf[1], kf[n][1], mfma16(qf[0], kf[n][0], fz));
    if (diag) {
#pragma unroll
      for (int n = 0; n < 4; ++n)
#pragma unroll
        for (int j = 0; j < 4; ++j)
          if (n * 16 + lr > w * 16 + lg * 4 + j) s4[n][j] = -1e30f;
    }

    // online softmax (row r = lg*4+j lives on the 16 lanes sharing lg)
    float pm[4];
#pragma unroll
    for (int j = 0; j < 4; ++j)
      pm[j] = fmaxf(fmaxf(s4[0][j], s4[1][j]), fmaxf(s4[2][j], s4[3][j]));
#pragma unroll
    for (int msk = 1; msk <= 8; msk <<= 1)
#pragma unroll
      for (int j = 0; j < 4; ++j) pm[j] = fmaxf(pm[j], __shfl_xor(pm[j], msk, 64));
    float alpha[4], rs[4];
#pragma unroll
    for (int j = 0; j < 4; ++j) {
      float mn = fmaxf(mrow[j], pm[j]);
      alpha[j] = __expf(mrow[j] - mn);
      mrow[j] = mn;
      rs[j] = 0.f;
    }
#pragma unroll
    for (int n = 0; n < 4; ++n)
#pragma unroll
      for (int j = 0; j < 4; ++j) {
        float p = __expf(s4[n][j] - mrow[j]);
        s4[n][j] = p;
        rs[j] += p;
      }
#pragma unroll
    for (int msk = 1; msk <= 8; msk <<= 1)
#pragma unroll
      for (int j = 0; j < 4; ++j) rs[j] += __shfl_xor(rs[j], msk, 64);
#pragma unroll
    for (int j = 0; j < 4; ++j) lrow[j] = lrow[j] * alpha[j] + rs[j];
#pragma unroll
    for (int nd = 0; nd < 4; ++nd)
#pragma unroll
      for (int j = 0; j < 4; ++j) o[nd][j] *= alpha[j];

    // P -> per-wave LDS (C-layout -> A-fragment layout)
#pragma unroll
    for (int n = 0; n < 4; ++n)
#pragma unroll
      for (int j = 0; j < 4; ++j)
        Pl[w][lg * 4 + j][n * 16 + lr] = (bf16)s4[n][j];

    // PV
#pragma unroll
    for (int kk = 0; kk < 2; ++kk) {
      bf16x8 pf = *reinterpret_cast<const bf16x8*>(&Pl[w][lr][kk * 32 + lg * 8]);
#pragma unroll
      for (int nd = 0; nd < 4; ++nd)
        o[nd] = mfma16(pf, vf[nd][kk], o[nd]);
    }
  }

  // normalize and write out
  float inv[4];
#pragma unroll
  for (int j = 0; j < 4; ++j) inv[j] = 1.0f / lrow[j];
  const int b = bh >> 4, h = bh & 15;
#pragma unroll
  for (int nd = 0; nd < 4; ++nd)
#pragma unroll
    for (int j = 0; j < 4; ++j) {
      int srow = qr0 + lg * 4 + j;
      int d = nd * 16 + lr;
      ctx[((long long)(b * SEQ + srow)) * DMODEL + h * HDIM + d] =
          (bf16)(o[nd][j] * inv[j]);
    }
}

extern "C" void kernel_launch(void* const* d_in, const int* in_sizes, int n_in,
                              void* d_out, int out_size, void* d_ws, size_t ws_size,
                              hipStream_t stream) {
  const float* x      = (const float*)d_in[0];
  const float* w_qkv  = (const float*)d_in[1];
  const float* w_proj = (const float*)d_in[2];
  const float* b_proj = (const float*)d_in[3];
  float* out = (float*)d_out;

  bf16* ws = (bf16*)d_ws;
  bf16* xb     = ws;                   // 4194304 elems
  bf16* wqkvb  = xb + 4194304;         // 3145728
  bf16* wprojb = wqkvb + 3145728;      // 1048576
  bf16* qb     = wprojb + 1048576;     // 4194304 (fragment-ordered, pre-scaled)
  bf16* kb     = qb + 4194304;         // 4194304 (fragment-ordered)
  bf16* vb     = kb + 4194304;         // 4194304 (V^T fragment-ordered)
  bf16* ctxb   = vb + 4194304;         // 4194304   total ~48 MB

  convert_all<<<8192, 256, 0, stream>>>(x, w_qkv, w_proj, xb);
  gemm_bt<0><<<dim3(32, 24), 256, 0, stream>>>(xb, wqkvb, 1024, qb, kb, vb, nullptr, nullptr);
  attn_kernel<<<dim3(32, 32), 256, 0, stream>>>(qb, kb, vb, ctxb);
  gemm_bt<1><<<dim3(32, 8), 256, 0, stream>>>(ctxb, wprojb, 1024, nullptr, nullptr, nullptr,
                                              b_proj, out);
}

// Round 6
// 200.112 us; speedup vs baseline: 1.2621x; 1.2621x over previous
//
#include <hip/hip_runtime.h>

#define SEQ    2048
#define NHEAD  16
#define HDIM   64
#define DMODEL 1024
#define BATCH  2

typedef __bf16 bf16;
typedef __bf16 bf16x8 __attribute__((ext_vector_type(8)));
typedef __bf16 bf16x4v __attribute__((ext_vector_type(4)));
typedef float  f32x4  __attribute__((ext_vector_type(4)));

typedef const __attribute__((address_space(1))) void* gas_ptr;
typedef __attribute__((address_space(3))) void*       las_ptr;

__device__ __forceinline__ f32x4 mfma16(bf16x8 a, bf16x8 b, f32x4 c) {
  return __builtin_amdgcn_mfma_f32_16x16x32_bf16(a, b, c, 0, 0, 0);
}

__device__ __forceinline__ void gload_lds16(const void* g, void* l) {
  __builtin_amdgcn_global_load_lds((gas_ptr)(unsigned long long)g,
                                   (las_ptr)(unsigned long long)l, 16, 0, 0);
}

// ---------------- fp32 -> bf16 conversion (x | w_qkv | w_proj concatenated) ----
__global__ void convert_all(const float* __restrict__ x, const float* __restrict__ wq,
                            const float* __restrict__ wp, bf16* __restrict__ out) {
  const long long NX = 4194304, NQ = 3145728, NP = 1048576;
  long long i = ((long long)blockIdx.x * blockDim.x + threadIdx.x) * 4;
  if (i >= NX + NQ + NP) return;
  const float* src; long long off;
  if (i < NX)           { src = x;  off = i; }
  else if (i < NX + NQ) { src = wq; off = i - NX; }
  else                  { src = wp; off = i - NX - NQ; }
  float4 f = *reinterpret_cast<const float4*>(src + off);
  bf16x4v r;
  r[0] = (bf16)f.x; r[1] = (bf16)f.y; r[2] = (bf16)f.z; r[3] = (bf16)f.w;
  *reinterpret_cast<bf16x4v*>(out + i) = r;
}

// ---------------- GEMM C = A(M,K) * B(N,K)^T, bf16 in, fp32 acc ---------------
// EPI 0: epilogue scatters Q/K (fragment-ordered, Q pre-scaled) and V^T
//        (fragment-ordered) so the attention kernel reads contiguous 1KB
//        fragments per wave. EPI 1: proj + bias, fp32 out.
template <int EPI>
__global__ __launch_bounds__(256) void gemm_bt(
    const bf16* __restrict__ A, const bf16* __restrict__ B, int K,
    bf16* __restrict__ q, bf16* __restrict__ k, bf16* __restrict__ v,
    const float* __restrict__ bias, float* __restrict__ out) {
  __shared__ alignas(16) bf16 As[2][128 * 32];
  __shared__ alignas(16) bf16 Bs[2][128 * 32];

  const int tid = threadIdx.x;
  const int l = tid & 63, w = tid >> 6;
  const int lr = l & 15, lg = l >> 4;
  const int wr = (w >> 1) * 64, wc = (w & 1) * 64;
  const long long m0 = (long long)blockIdx.x * 128;
  const long long n0 = (long long)blockIdx.y * 128;
  const int crow = tid >> 2, ccol = (tid & 3) * 8;

  auto stage = [&](int kt, int buf) {
    const bf16* a_src = A + (m0 + crow) * K + (long long)kt * 32 + ccol;
    const bf16* b_src = B + (n0 + crow) * K + (long long)kt * 32 + ccol;
    gload_lds16(a_src,           &As[buf][tid * 8]);
    gload_lds16(a_src + 64LL * K, &As[buf][(tid + 256) * 8]);
    gload_lds16(b_src,           &Bs[buf][tid * 8]);
    gload_lds16(b_src + 64LL * K, &Bs[buf][(tid + 256) * 8]);
  };

  f32x4 acc[4][4];
  const f32x4 fz = {0.f, 0.f, 0.f, 0.f};
#pragma unroll
  for (int m = 0; m < 4; ++m)
#pragma unroll
    for (int n = 0; n < 4; ++n) acc[m][n] = fz;

  stage(0, 0);
  const int nk = K >> 5;
  int cur = 0;
  for (int kt = 0; kt < nk; ++kt) {
    __syncthreads();  // drains vmcnt: buf[cur] staged; prev compute done
    if (kt + 1 < nk) stage(kt + 1, cur ^ 1);
    bf16x8 af[4], bfv[4];
#pragma unroll
    for (int m = 0; m < 4; ++m)
      af[m] = *reinterpret_cast<const bf16x8*>(&As[cur][(wr + m * 16 + lr) * 32 + lg * 8]);
#pragma unroll
    for (int n = 0; n < 4; ++n)
      bfv[n] = *reinterpret_cast<const bf16x8*>(&Bs[cur][(wc + n * 16 + lr) * 32 + lg * 8]);
#pragma unroll
    for (int m = 0; m < 4; ++m)
#pragma unroll
      for (int n = 0; n < 4; ++n) acc[m][n] = mfma16(af[m], bfv[n], acc[m][n]);
    cur ^= 1;
  }

#pragma unroll
  for (int m = 0; m < 4; ++m) {
#pragma unroll
    for (int n = 0; n < 4; ++n) {
#pragma unroll
      for (int j = 0; j < 4; ++j) {
        long long grow = m0 + wr + m * 16 + lg * 4 + j;   // row in (B*S)
        long long gcol = n0 + wc + n * 16 + lr;           // col in N
        float val = acc[m][n][j];
        if (EPI == 0) {
          int three = (int)(gcol >> 10);
          int rem = (int)(gcol & 1023);
          int h = rem >> 6, d = rem & 63;
          int b = (int)(grow >> 11), s = (int)(grow & 2047);
          int bh = b * NHEAD + h;
          if (three < 2) {
            // Q/K fragment order: [bh][s/16][d/32][ (s&15)*32 + ((d>>3)&3)*8 + (d&7) ]
            int dst = ((bh * 128 + (s >> 4)) * 2 + (d >> 5)) * 512 +
                      (s & 15) * 32 + ((d >> 3) & 3) * 8 + (d & 7);
            if (three == 0) q[dst] = (bf16)(val * 0.125f);   // pre-scale Q
            else            k[dst] = (bf16)val;
          } else {
            // V^T fragment order: [bh][d/16][s/64][(s>>5)&1][ (d&15)*32 + ((s>>3)&3)*8 + (s&7) ]
            int dst = (((bh * 4 + (d >> 4)) * 32 + (s >> 6)) * 2 + ((s >> 5) & 1)) * 512 +
                      (d & 15) * 32 + ((s >> 3) & 3) * 8 + (s & 7);
            v[dst] = (bf16)val;
          }
        } else {
          out[grow * 1024 + gcol] = val + bias[gcol];
        }
      }
    }
  }
}

// ---------------- causal flash attention, bf16, hd=64 -------------------------
// Barrier-free waves; fragment-ordered global reads (round-5 proven indexing).
// Round-6 changes ONLY:
//  (1) uniform pairing: block handles q-groups {p, 31-p} sequentially ->
//      every wave does exactly 33 key-tile iterations (no causal tail).
//  (2) __launch_bounds__(256,2): 128-VGPR budget so the whole working set
//      stays in arch VGPRs (round 5's (256,4) forced 64 VGPR -> AGPR churn).
__global__ __launch_bounds__(256, 2) void attn_kernel(
    const bf16* __restrict__ qbuf, const bf16* __restrict__ kbuf,
    const bf16* __restrict__ vbuf, bf16* __restrict__ ctx) {
  const int lid = blockIdx.y * gridDim.x + blockIdx.x;  // [0,512)
  const int xcd = lid & 7;
  const int idx = lid >> 3;                             // [0,64)
  const int bh  = xcd + (idx >> 4) * 8;                 // 4 bh per XCD; K+V 2MB/XCD (L2-fit)
  const int p   = idx & 15;                             // pair index [0,16)
  const int tid = threadIdx.x;
  const int l = tid & 63, w = tid >> 6;
  const int lr = l & 15, lg = l >> 4;
  const int foff = lr * 32 + lg * 8;

  __shared__ alignas(16) bf16 Pl[4][16][72];   // 144B row stride: 16B-aligned b128

  const bf16* Kb = kbuf + bh * 131072 + foff;          // bh*128*2*512
  const bf16* Vb = vbuf + bh * 131072 + foff;          // bh*4*32*2*512
  const int b = bh >> 4, h = bh & 15;
  const f32x4 fz = {0.f, 0.f, 0.f, 0.f};

#pragma unroll
  for (int phase = 0; phase < 2; ++phase) {
    const int qg = phase ? (31 - p) : p;       // 64-row q-group
    const int qt16 = qg * 4 + w;               // wave's 16-row q-tile
    const int qr0 = qt16 * 16;

    const bf16* Qb = qbuf + (bh * 128 + qt16) * 1024 + foff;
    bf16x8 qf[2];
    qf[0] = *reinterpret_cast<const bf16x8*>(Qb);
    qf[1] = *reinterpret_cast<const bf16x8*>(Qb + 512);

    f32x4 o[4];
    float mrow[4], lrow[4];
#pragma unroll
    for (int nd = 0; nd < 4; ++nd) o[nd] = fz;
#pragma unroll
    for (int j = 0; j < 4; ++j) { mrow[j] = -1e30f; lrow[j] = 0.f; }

    for (int kt = 0; kt <= qg; ++kt) {
      const bool diag = (kt == qg);

      // V^T fragments first (consumed last -> deepest in flight)
      bf16x8 vf[4][2];
#pragma unroll
      for (int nd = 0; nd < 4; ++nd)
#pragma unroll
        for (int kk = 0; kk < 2; ++kk)
          vf[nd][kk] = *reinterpret_cast<const bf16x8*>(
              &Vb[((nd * 32 + kt) * 2 + kk) * 512]);

      // K fragments (unconditional; in-bounds)
      bf16x8 kf[4][2];
#pragma unroll
      for (int n = 0; n < 4; ++n)
#pragma unroll
        for (int kk = 0; kk < 2; ++kk)
          kf[n][kk] = *reinterpret_cast<const bf16x8*>(
              &Kb[((kt * 4 + n) * 2 + kk) * 512]);

      // QK^T, then elementwise causal mask on the diagonal tile
      f32x4 s4[4];
#pragma unroll
      for (int n = 0; n < 4; ++n)
        s4[n] = mfma16(qf[1], kf[n][1], mfma16(qf[0], kf[n][0], fz));
      if (diag) {
#pragma unroll
        for (int n = 0; n < 4; ++n)
#pragma unroll
          for (int j = 0; j < 4; ++j)
            if (n * 16 + lr > w * 16 + lg * 4 + j) s4[n][j] = -1e30f;
      }

      // online softmax (row r = lg*4+j lives on the 16 lanes sharing lg)
      float pm[4];
#pragma unroll
      for (int j = 0; j < 4; ++j)
        pm[j] = fmaxf(fmaxf(s4[0][j], s4[1][j]), fmaxf(s4[2][j], s4[3][j]));
#pragma unroll
      for (int msk = 1; msk <= 8; msk <<= 1)
#pragma unroll
        for (int j = 0; j < 4; ++j) pm[j] = fmaxf(pm[j], __shfl_xor(pm[j], msk, 64));
      float alpha[4], rs[4];
#pragma unroll
      for (int j = 0; j < 4; ++j) {
        float mn = fmaxf(mrow[j], pm[j]);
        alpha[j] = __expf(mrow[j] - mn);
        mrow[j] = mn;
        rs[j] = 0.f;
      }
#pragma unroll
      for (int n = 0; n < 4; ++n)
#pragma unroll
        for (int j = 0; j < 4; ++j) {
          float pv = __expf(s4[n][j] - mrow[j]);
          s4[n][j] = pv;
          rs[j] += pv;
        }
#pragma unroll
      for (int msk = 1; msk <= 8; msk <<= 1)
#pragma unroll
        for (int j = 0; j < 4; ++j) rs[j] += __shfl_xor(rs[j], msk, 64);
#pragma unroll
      for (int j = 0; j < 4; ++j) lrow[j] = lrow[j] * alpha[j] + rs[j];
#pragma unroll
      for (int nd = 0; nd < 4; ++nd)
#pragma unroll
        for (int j = 0; j < 4; ++j) o[nd][j] *= alpha[j];

      // P -> per-wave LDS (C-layout -> A-fragment layout)
#pragma unroll
      for (int n = 0; n < 4; ++n)
#pragma unroll
        for (int j = 0; j < 4; ++j)
          Pl[w][lg * 4 + j][n * 16 + lr] = (bf16)s4[n][j];

      // PV
#pragma unroll
      for (int kk = 0; kk < 2; ++kk) {
        bf16x8 pf = *reinterpret_cast<const bf16x8*>(&Pl[w][lr][kk * 32 + lg * 8]);
#pragma unroll
        for (int nd = 0; nd < 4; ++nd)
          o[nd] = mfma16(pf, vf[nd][kk], o[nd]);
      }
    }

    // normalize and write out this q-tile
    float inv[4];
#pragma unroll
    for (int j = 0; j < 4; ++j) inv[j] = 1.0f / lrow[j];
#pragma unroll
    for (int nd = 0; nd < 4; ++nd)
#pragma unroll
      for (int j = 0; j < 4; ++j) {
        int srow = qr0 + lg * 4 + j;
        int d = nd * 16 + lr;
        ctx[((long long)(b * SEQ + srow)) * DMODEL + h * HDIM + d] =
            (bf16)(o[nd][j] * inv[j]);
      }
  }
}

extern "C" void kernel_launch(void* const* d_in, const int* in_sizes, int n_in,
                              void* d_out, int out_size, void* d_ws, size_t ws_size,
                              hipStream_t stream) {
  const float* x      = (const float*)d_in[0];
  const float* w_qkv  = (const float*)d_in[1];
  const float* w_proj = (const float*)d_in[2];
  const float* b_proj = (const float*)d_in[3];
  float* out = (float*)d_out;

  bf16* ws = (bf16*)d_ws;
  bf16* xb     = ws;                   // 4194304 elems
  bf16* wqkvb  = xb + 4194304;         // 3145728
  bf16* wprojb = wqkvb + 3145728;      // 1048576
  bf16* qb     = wprojb + 1048576;     // 4194304 (fragment-ordered, pre-scaled)
  bf16* kb     = qb + 4194304;         // 4194304 (fragment-ordered)
  bf16* vb     = kb + 4194304;         // 4194304 (V^T fragment-ordered)
  bf16* ctxb   = vb + 4194304;         // 4194304   total ~48 MB

  convert_all<<<8192, 256, 0, stream>>>(x, w_qkv, w_proj, xb);
  gemm_bt<0><<<dim3(32, 24), 256, 0, stream>>>(xb, wqkvb, 1024, qb, kb, vb, nullptr, nullptr);
  attn_kernel<<<dim3(16, 32), 256, 0, stream>>>(qb, kb, vb, ctxb);
  gemm_bt<1><<<dim3(32, 8), 256, 0, stream>>>(ctxb, wprojb, 1024, nullptr, nullptr, nullptr,
                                              b_proj, out);
}